// Round 1
// baseline (158.123 us; speedup 1.0000x reference)
//
#include <hip/hip_runtime.h>
#include <hip/hip_bf16.h>

// Word2Vec fused loss: L=4096, V=32000, D=128, WINDOW=5, centers M=4086 (pad 4096)
// loss = sum_i [ logsumexp_v(ctx_mean_i . W_v) - ctx_mean_i . W_{tgt_i} ]
// Max logit ~22 -> exp fits fp32; no online-max needed.

#define NCTR 4086
#define WIN 5
#define VOC 32000
#define DIM 128
#define MPAD 4096

typedef __attribute__((ext_vector_type(8))) __bf16 bf16x8;
typedef __attribute__((ext_vector_type(4))) __bf16 bf16x4;
typedef __attribute__((ext_vector_type(4))) float f32x4;

// ws layout (bytes):
//   [0,        8192000)  Wb   : bf16 VOC*DIM
//   [8192000,  9240576)  A    : bf16 MPAD*DIM (ctx_mean, rows >=NCTR zeroed)
//   [9240576,  9256960)  expsum: float MPAD
//   [9256960,  9273344)  tgt  : float MPAD (target logit per row)
#define WS_A      8192000
#define WS_EXPSUM 9240576
#define WS_TGT    9256960

__global__ __launch_bounds__(256) void k_wconv(const float* __restrict__ W,
                                               __bf16* __restrict__ Wb) {
    int i = blockIdx.x * 256 + threadIdx.x;      // processes 4 elements
    f32x4 v = ((const f32x4*)W)[i];
    bf16x4 o;
    o.x = (__bf16)v.x; o.y = (__bf16)v.y; o.z = (__bf16)v.z; o.w = (__bf16)v.w;
    ((bf16x4*)Wb)[i] = o;
}

__global__ __launch_bounds__(128) void k_ctx(const int* __restrict__ tokens,
                                             const float* __restrict__ emb,
                                             const float* __restrict__ W,
                                             __bf16* __restrict__ A,
                                             float* __restrict__ tgt,
                                             float* __restrict__ expsum) {
    int i = blockIdx.x;
    int d = threadIdx.x;
    if (d == 0) expsum[i] = 0.0f;
    if (i >= NCTR) {
        A[i * DIM + d] = (__bf16)0.0f;
        if (d == 0) tgt[i] = 0.0f;
        return;
    }
    int p = i + WIN;
    float s = 0.0f;
#pragma unroll
    for (int o = 1; o <= WIN; ++o) {
        s += emb[(long)tokens[p - o] * DIM + d];
        s += emb[(long)tokens[p + o] * DIM + d];
    }
    float m = s * 0.1f;
    A[i * DIM + d] = (__bf16)m;
    // target logit (fp32)
    float prod = m * W[(long)tokens[p] * DIM + d];
#pragma unroll
    for (int off = 32; off; off >>= 1) prod += __shfl_down(prod, off);
    __shared__ float red[2];
    if ((d & 63) == 0) red[d >> 6] = prod;
    __syncthreads();
    if (d == 0) tgt[i] = red[0] + red[1];
}

// Each wave: 64 M-rows (4 x 16 subtiles) x 16 N-cols per step, K=128 (4 MFMAs/acc).
// Streams 25 steps of 16 cols; 80 streams (blockIdx.y*4+wave) cover all 2000 col-steps.
__global__ __launch_bounds__(256) void k_gemm(const __bf16* __restrict__ A,
                                              const __bf16* __restrict__ Wb,
                                              float* __restrict__ expsum) {
    const int lane = threadIdx.x & 63;
    const int wv   = threadIdx.x >> 6;
    const int lrow = lane & 15;
    const int quad = lane >> 4;
    const int m0   = blockIdx.x * 64;
    const int sid  = blockIdx.y * 4 + wv;   // 0..79

    // A-frags: A[m = m0+ms*16+lrow][k = kb*32 + quad*8 + j], held in regs for whole kernel
    const bf16x8* Ap = (const bf16x8*)A + (long)(m0 + lrow) * 16 + quad;
    bf16x8 a[4][4];
#pragma unroll
    for (int ms = 0; ms < 4; ++ms)
#pragma unroll
        for (int kb = 0; kb < 4; ++kb)
            a[ms][kb] = Ap[ms * 256 + kb * 4];

    const bf16x8* Wp = (const bf16x8*)Wb + lrow * 16 + quad;
    long base = (long)sid * 256;            // (row n0+lrow) * 128 elems / 8
    bf16x8 b[4];
#pragma unroll
    for (int kb = 0; kb < 4; ++kb) b[kb] = Wp[base + kb * 4];

    float run[4][4];
#pragma unroll
    for (int ms = 0; ms < 4; ++ms)
#pragma unroll
        for (int r = 0; r < 4; ++r) run[ms][r] = 0.0f;

    for (int t = 0; t < 25; ++t) {
        long nb = base + 80 * 256;
        bf16x8 bn[4];
        // prefetch next step's B-frags; at t==24 this overreads past Wb but stays
        // inside ws (lands in the A region, <= 8.53 MB < 9.24 MB) -- values unused.
#pragma unroll
        for (int kb = 0; kb < 4; ++kb) bn[kb] = Wp[nb + kb * 4];

        f32x4 acc[4];
        f32x4 z = {0.0f, 0.0f, 0.0f, 0.0f};
#pragma unroll
        for (int ms = 0; ms < 4; ++ms) acc[ms] = z;
#pragma unroll
        for (int kb = 0; kb < 4; ++kb)
#pragma unroll
            for (int ms = 0; ms < 4; ++ms)
                acc[ms] = __builtin_amdgcn_mfma_f32_16x16x32_bf16(a[ms][kb], b[kb], acc[ms], 0, 0, 0);

        // fused exp + per-(row,collane) running sum
#pragma unroll
        for (int ms = 0; ms < 4; ++ms)
#pragma unroll
            for (int r = 0; r < 4; ++r)
                run[ms][r] += __expf(acc[ms][r]);

#pragma unroll
        for (int kb = 0; kb < 4; ++kb) b[kb] = bn[kb];
        base = nb;
    }

    // reduce across the 16 col-lanes (same quad group), then one atomic per row
#pragma unroll
    for (int ms = 0; ms < 4; ++ms)
#pragma unroll
        for (int r = 0; r < 4; ++r) {
            float v = run[ms][r];
            v += __shfl_xor(v, 1);
            v += __shfl_xor(v, 2);
            v += __shfl_xor(v, 4);
            v += __shfl_xor(v, 8);
            if (lrow == 0) atomicAdd(&expsum[m0 + ms * 16 + quad * 4 + r], v);
        }
}

__global__ __launch_bounds__(256) void k_fin(const float* __restrict__ expsum,
                                             const float* __restrict__ tgt,
                                             float* __restrict__ out) {
    float s = 0.0f;
    for (int i = threadIdx.x; i < NCTR; i += 256)
        s += __logf(expsum[i]) - tgt[i];
#pragma unroll
    for (int off = 32; off; off >>= 1) s += __shfl_down(s, off);
    __shared__ float red[4];
    if ((threadIdx.x & 63) == 0) red[threadIdx.x >> 6] = s;
    __syncthreads();
    if (threadIdx.x == 0) out[0] = red[0] + red[1] + red[2] + red[3];
}

extern "C" void kernel_launch(void* const* d_in, const int* in_sizes, int n_in,
                              void* d_out, int out_size, void* d_ws, size_t ws_size,
                              hipStream_t stream) {
    const int*   tokens = (const int*)d_in[0];
    const float* emb    = (const float*)d_in[1];
    const float* W      = (const float*)d_in[2];
    float* out = (float*)d_out;
    char* ws = (char*)d_ws;
    __bf16* Wb     = (__bf16*)ws;
    __bf16* A      = (__bf16*)(ws + WS_A);
    float*  expsum = (float*)(ws + WS_EXPSUM);
    float*  tgt    = (float*)(ws + WS_TGT);

    k_wconv<<<dim3(VOC * DIM / 4 / 256), 256, 0, stream>>>(W, Wb);          // 4000 blocks
    k_ctx  <<<dim3(MPAD), 128, 0, stream>>>(tokens, emb, W, A, tgt, expsum);
    k_gemm <<<dim3(64, 20), 256, 0, stream>>>(A, Wb, expsum);               // 1280 blocks
    k_fin  <<<dim3(1), 256, 0, stream>>>(expsum, tgt, out);
}